// Round 1
// baseline (451.011 us; speedup 1.0000x reference)
//
#include <hip/hip_runtime.h>
#include <hip/hip_bf16.h>

#define DEVI __device__ __forceinline__

typedef __attribute__((ext_vector_type(4))) float f32x4;
typedef __attribute__((ext_vector_type(8))) short bf16x8;

constexpr int Bb = 4, Tt = 2048, Cc = 1024, Hh = 16, HDd = 64;
constexpr int Mm = Bb * Tt; // 8192

// ---- bf16 helpers (bit-level, no reliance on __hip_bfloat16 internals) ----
DEVI short f2bf(float f) {
    union { float f; unsigned u; } x; x.f = f;
    unsigned r = x.u + 0x7FFFu + ((x.u >> 16) & 1u); // round-nearest-even
    return (short)(r >> 16);
}

DEVI void gload_lds16(const void* g, void* l) {
    __builtin_amdgcn_global_load_lds(
        (const __attribute__((address_space(1))) unsigned int*)g,
        (__attribute__((address_space(3))) unsigned int*)l, 16, 0, 0);
}

// ---------------- fp32 -> bf16 conversion ----------------
__global__ void cvt_kernel(const float* __restrict__ s, short* __restrict__ d, int n8) {
    int i = blockIdx.x * 256 + threadIdx.x;
    if (i < n8) {
        const float4* sp = (const float4*)s;
        float4 a = sp[2 * i], b = sp[2 * i + 1];
        short tmp[8];
        tmp[0] = f2bf(a.x); tmp[1] = f2bf(a.y); tmp[2] = f2bf(a.z); tmp[3] = f2bf(a.w);
        tmp[4] = f2bf(b.x); tmp[5] = f2bf(b.y); tmp[6] = f2bf(b.z); tmp[7] = f2bf(b.w);
        *(bf16x8*)(d + 8 * (size_t)i) = *(bf16x8*)tmp;
    }
}

// ---------------- GEMM: C[M][N] = A[M][K] * Bw[N][K]^T + bias ----------------
template<typename OutT> DEVI OutT cvt_out(float v);
template<> DEVI float cvt_out<float>(float v) { return v; }
template<> DEVI short cvt_out<short>(float v) { return f2bf(v); }

template<typename OutT>
__global__ __launch_bounds__(256, 2)
void gemm_bt(const short* __restrict__ A, const short* __restrict__ Bw,
             const float* __restrict__ bias, OutT* __restrict__ Cout,
             int Mdim, int Ndim, int Kdim)
{
    constexpr int BM = 128, BN = 128, BK = 64;
    __shared__ __align__(16) short As[BM][BK];
    __shared__ __align__(16) short Bs[BN][BK];
    const int bm = blockIdx.x * BM;
    const int bn = blockIdx.y * BN;
    const int tid = threadIdx.x;
    const int lane = tid & 63, wid = tid >> 6;
    const int wr = wid >> 1, wc = wid & 1; // 2x2 waves -> 64x64 each

    f32x4 acc[4][4] = {};

    const int lrow = lane >> 3;        // row within 8-row chunk
    const int lcol = (lane & 7) * 8;   // bf16 column offset (16B per lane)

    for (int k0 = 0; k0 < Kdim; k0 += BK) {
        #pragma unroll
        for (int c = 0; c < 4; ++c) {
            const int chunk = wid * 4 + c;        // 0..15, 8 rows each
            const int row = chunk * 8 + lrow;
            gload_lds16(A  + (size_t)(bm + row) * Kdim + k0 + lcol, &As[chunk * 8][0]);
            gload_lds16(Bw + (size_t)(bn + row) * Kdim + k0 + lcol, &Bs[chunk * 8][0]);
        }
        __syncthreads();
        const int rr = lane & 15;
        #pragma unroll
        for (int kk = 0; kk < BK; kk += 32) {
            const int koff = kk + (lane >> 4) * 8;
            bf16x8 af[4], bfr[4];
            #pragma unroll
            for (int m_ = 0; m_ < 4; ++m_)
                af[m_] = *(const bf16x8*)&As[wr * 64 + m_ * 16 + rr][koff];
            #pragma unroll
            for (int n_ = 0; n_ < 4; ++n_)
                bfr[n_] = *(const bf16x8*)&Bs[wc * 64 + n_ * 16 + rr][koff];
            #pragma unroll
            for (int m_ = 0; m_ < 4; ++m_)
                #pragma unroll
                for (int n_ = 0; n_ < 4; ++n_)
                    acc[m_][n_] = __builtin_amdgcn_mfma_f32_16x16x32_bf16(
                        af[m_], bfr[n_], acc[m_][n_], 0, 0, 0);
        }
        __syncthreads();
    }

    // epilogue: D layout col = lane&15, row = (lane>>4)*4 + i
    const int cidx = lane & 15;
    const int r4 = (lane >> 4) * 4;
    #pragma unroll
    for (int n_ = 0; n_ < 4; ++n_) {
        const int col = bn + wc * 64 + n_ * 16 + cidx;
        const float bv = bias[col];
        #pragma unroll
        for (int m_ = 0; m_ < 4; ++m_) {
            const int rowb = bm + wr * 64 + m_ * 16 + r4;
            #pragma unroll
            for (int i = 0; i < 4; ++i)
                Cout[(size_t)(rowb + i) * Ndim + col] = cvt_out<OutT>(acc[m_][n_][i] + bv);
        }
    }
}

// ---------------- Flash attention (causal) ----------------
// grid: (T/64, B*H); block 256 = 4 waves, each wave owns 16 q-rows.
__global__ __launch_bounds__(256, 2)
void attn_kernel(const short* __restrict__ Q, const short* __restrict__ K,
                 const short* __restrict__ V, short* __restrict__ O)
{
    constexpr int QT = 64, KT = 64, PAD = 72;
    const int qt = blockIdx.x;
    const int bh = blockIdx.y;
    const int b = bh / Hh, h = bh % Hh;
    const size_t baseRow = (size_t)b * Tt;
    const int q0 = qt * QT;

    const int tid = threadIdx.x, lane = tid & 63, wid = tid >> 6;
    const int rr = lane & 15;
    const int koff = (lane >> 4) * 8;

    __shared__ __align__(16) short Ks[KT][PAD];
    __shared__ __align__(16) short Vt[HDd][PAD];
    __shared__ __align__(16) short Ps[4][16][PAD];

    // Q fragments: wave's rows are q0 + wid*16 + (lane&15)
    const int qrow = q0 + wid * 16 + rr;
    const short* qptr = Q + (baseRow + qrow) * Cc + h * HDd + koff;
    bf16x8 qf0 = *(const bf16x8*)qptr;
    bf16x8 qf1 = *(const bf16x8*)(qptr + 32);

    f32x4 oacc[4] = {};
    float mrow[4], lsum[4];
    #pragma unroll
    for (int i = 0; i < 4; ++i) { mrow[i] = -3.0e38f; lsum[i] = 0.f; }

    const float SCL = 0.125f * 1.44269504088896f; // 1/sqrt(64) * log2(e)
    const int nkv = qt + 1;

    for (int kt = 0; kt < nkv; ++kt) {
        const int kv0 = kt * KT;
        // cooperative staging: K row-major, V transposed
        for (int c = tid; c < 512; c += 256) {
            const int row = c >> 3;
            const int col8 = (c & 7) * 8;
            const size_t gbase = (baseRow + kv0 + row) * Cc + h * HDd + col8;
            *(bf16x8*)&Ks[row][col8] = *(const bf16x8*)(K + gbase);
            bf16x8 vv = *(const bf16x8*)(V + gbase);
            #pragma unroll
            for (int j = 0; j < 8; ++j)
                Vt[col8 + j][row] = ((short*)&vv)[j];
        }
        __syncthreads();

        // S = Q K^T  (per wave: 16 q-rows x 64 kv-cols)
        f32x4 sacc[4] = {};
        #pragma unroll
        for (int n = 0; n < 4; ++n) {
            bf16x8 kf0 = *(const bf16x8*)&Ks[n * 16 + rr][koff];
            bf16x8 kf1 = *(const bf16x8*)&Ks[n * 16 + rr][32 + koff];
            sacc[n] = __builtin_amdgcn_mfma_f32_16x16x32_bf16(qf0, kf0, sacc[n], 0, 0, 0);
            sacc[n] = __builtin_amdgcn_mfma_f32_16x16x32_bf16(qf1, kf1, sacc[n], 0, 0, 0);
        }

        // scale + causal mask + online softmax
        const bool diag = (kt == nkv - 1);
        const int myq = q0 + wid * 16 + (lane >> 4) * 4;
        float p[4][4]; // [n][i]
        float tmax[4];
        #pragma unroll
        for (int i = 0; i < 4; ++i) {
            float mx = -3.0e38f;
            #pragma unroll
            for (int n = 0; n < 4; ++n) {
                float s = sacc[n][i] * SCL;
                if (diag && (kv0 + n * 16 + rr > myq + i)) s = -3.0e38f;
                p[n][i] = s;
                mx = fmaxf(mx, s);
            }
            tmax[i] = mx;
        }
        #pragma unroll
        for (int d = 1; d < 16; d <<= 1) {
            #pragma unroll
            for (int i = 0; i < 4; ++i)
                tmax[i] = fmaxf(tmax[i], __shfl_xor(tmax[i], d, 64));
        }
        float alpha[4];
        #pragma unroll
        for (int i = 0; i < 4; ++i) {
            const float mnew = fmaxf(mrow[i], tmax[i]);
            alpha[i] = exp2f(mrow[i] - mnew);
            mrow[i] = mnew;
            float rs = 0.f;
            #pragma unroll
            for (int n = 0; n < 4; ++n) {
                const float pe = exp2f(p[n][i] - mnew);
                p[n][i] = pe;
                rs += pe;
            }
            #pragma unroll
            for (int d = 1; d < 16; d <<= 1) rs += __shfl_xor(rs, d, 64);
            lsum[i] = lsum[i] * alpha[i] + rs;
        }
        #pragma unroll
        for (int n = 0; n < 4; ++n)
            #pragma unroll
            for (int i = 0; i < 4; ++i)
                oacc[n][i] *= alpha[i];

        // P -> per-wave LDS (bf16), then PV
        #pragma unroll
        for (int i = 0; i < 4; ++i)
            #pragma unroll
            for (int n = 0; n < 4; ++n)
                Ps[wid][(lane >> 4) * 4 + i][n * 16 + rr] = f2bf(p[n][i]);

        #pragma unroll
        for (int n = 0; n < 4; ++n) { // d-block
            #pragma unroll
            for (int c2 = 0; c2 < 2; ++c2) {
                bf16x8 pf = *(const bf16x8*)&Ps[wid][rr][c2 * 32 + koff];
                bf16x8 vf = *(const bf16x8*)&Vt[n * 16 + rr][c2 * 32 + koff];
                oacc[n] = __builtin_amdgcn_mfma_f32_16x16x32_bf16(pf, vf, oacc[n], 0, 0, 0);
            }
        }
        __syncthreads();
    }

    // epilogue: O[q][h*64 + d]
    #pragma unroll
    for (int n = 0; n < 4; ++n) {
        #pragma unroll
        for (int i = 0; i < 4; ++i) {
            const float v = oacc[n][i] / lsum[i];
            O[(baseRow + q0 + wid * 16 + (lane >> 4) * 4 + i) * Cc + h * HDd + n * 16 + rr] = f2bf(v);
        }
    }
}

// ---------------- host ----------------
extern "C" void kernel_launch(void* const* d_in, const int* in_sizes, int n_in,
                              void* d_out, int out_size, void* d_ws, size_t ws_size,
                              hipStream_t stream) {
    (void)in_sizes; (void)n_in; (void)out_size; (void)ws_size;
    const float* x  = (const float*)d_in[0];
    const float* Wq = (const float*)d_in[1];
    const float* bq = (const float*)d_in[2];
    const float* Wk = (const float*)d_in[3];
    const float* bk = (const float*)d_in[4];
    const float* Wv = (const float*)d_in[5];
    const float* bv = (const float*)d_in[6];
    const float* Wo = (const float*)d_in[7];
    const float* bo = (const float*)d_in[8];
    float* out = (float*)d_out;

    short* ws  = (short*)d_ws;
    short* xb  = ws;
    short* wqb = xb  + (size_t)Mm * Cc;
    short* wkb = wqb + (size_t)Cc * Cc;
    short* wvb = wkb + (size_t)Cc * Cc;
    short* wob = wvb + (size_t)Cc * Cc;
    short* Qb  = wob + (size_t)Cc * Cc;
    short* Kb  = Qb  + (size_t)Mm * Cc;
    short* Vb  = Kb  + (size_t)Mm * Cc;
    short* Ob  = Vb  + (size_t)Mm * Cc;

    const int nx8 = Mm * Cc / 8;   // 1048576
    const int nw8 = Cc * Cc / 8;   // 131072
    cvt_kernel<<<(nx8 + 255) / 256, 256, 0, stream>>>(x,  xb,  nx8);
    cvt_kernel<<<(nw8 + 255) / 256, 256, 0, stream>>>(Wq, wqb, nw8);
    cvt_kernel<<<(nw8 + 255) / 256, 256, 0, stream>>>(Wk, wkb, nw8);
    cvt_kernel<<<(nw8 + 255) / 256, 256, 0, stream>>>(Wv, wvb, nw8);
    cvt_kernel<<<(nw8 + 255) / 256, 256, 0, stream>>>(Wo, wob, nw8);

    dim3 g(Mm / 128, Cc / 128);
    gemm_bt<short><<<g, 256, 0, stream>>>(xb, wqb, bq, Qb, Mm, Cc, Cc);
    gemm_bt<short><<<g, 256, 0, stream>>>(xb, wkb, bk, Kb, Mm, Cc, Cc);
    gemm_bt<short><<<g, 256, 0, stream>>>(xb, wvb, bv, Vb, Mm, Cc, Cc);

    attn_kernel<<<dim3(Tt / 64, Bb * Hh), 256, 0, stream>>>(Qb, Kb, Vb, Ob);

    gemm_bt<float><<<g, 256, 0, stream>>>(Ob, wob, bo, out, Mm, Cc, Cc);
}